// Round 15
// baseline (126.066 us; speedup 1.0000x reference)
//
#include <hip/hip_runtime.h>
#include <hip/hip_bf16.h>

typedef __attribute__((ext_vector_type(8))) short short8;       // 8 x bf16 (4 VGPR)
typedef __attribute__((ext_vector_type(4))) float f32x4;        // MFMA acc / float4
typedef __attribute__((ext_vector_type(2))) float f32x2;
typedef __attribute__((ext_vector_type(4))) unsigned short ushort4v;
typedef __attribute__((ext_vector_type(2))) unsigned int uint32x2;

__device__ __forceinline__ unsigned short f2bf(float f) {
    __hip_bfloat16 h = __float2bfloat16(f);
    return __builtin_bit_cast(unsigned short, h);
}
__device__ __forceinline__ unsigned int pack2(float a, float b) {
    return (unsigned int)f2bf(a) | ((unsigned int)f2bf(b) << 16);
}
__device__ __forceinline__ unsigned int pk_fp8x4(float a0, float a1, float a2, float a3) {
    int v = 0;
    v = __builtin_amdgcn_cvt_pk_fp8_f32(a0, a1, v, false);   // bytes 0,1
    v = __builtin_amdgcn_cvt_pk_fp8_f32(a2, a3, v, true);    // bytes 2,3
    return (unsigned int)v;
}
__device__ __forceinline__ void gload_lds16(const void* g, void* l) {
    __builtin_amdgcn_global_load_lds((const __attribute__((address_space(1))) unsigned int*)g,
                                     (__attribute__((address_space(3))) unsigned int*)l, 16, 0, 0);
}

#define VMCNT(N) asm volatile("s_waitcnt vmcnt(" #N ")" ::: "memory")
#define LGKM0()  asm volatile("s_waitcnt lgkmcnt(0)" ::: "memory")

// ---------------- K0: W fp32 [256][512] -> wt bf16 tiled+bank-swizzled (R14 verbatim) ----
__global__ __launch_bounds__(256) void k0_wt(const float* __restrict__ w,
                                             unsigned short* __restrict__ wt) {
    int T = blockIdx.x * 256 + threadIdx.x;     // 0..16383 slots
    int c = T & 255, u = T >> 8;
    const float* s = w + c * 512 + u * 8;
    f32x4 a = *(const f32x4*)s;
    f32x4 b = *(const f32x4*)(s + 4);
    short8 o;
    o[0] = (short)f2bf(a[0]); o[1] = (short)f2bf(a[1]);
    o[2] = (short)f2bf(a[2]); o[3] = (short)f2bf(a[3]);
    o[4] = (short)f2bf(b[0]); o[5] = (short)f2bf(b[1]);
    o[6] = (short)f2bf(b[2]); o[7] = (short)f2bf(b[3]);
    size_t off = (size_t)(((u * 256 + c) * 16) ^ ((u & 3) << 4));
    *(short8*)((char*)wt + off) = o;
}

// ---------------- K1: Q-GEMM + normalize (R14 verbatim) ----------------
__global__ __launch_bounds__(256, 2) void k1_qgemm(const float* __restrict__ x,
                                                   const unsigned short* __restrict__ wt,
                                                   unsigned char* __restrict__ qn) {
    const int blk = blockIdx.x;
    const int b_  = blk >> 5;
    const int wh  = (blk >> 4) & 1;
    const int rb  = blk & 15;
    const int winbase = b_ * 4 + wh * 2;

    __shared__ __align__(16) char smem[65536];

    const int tid  = threadIdx.x;
    const int lane = tid & 63;
    const int wv   = tid >> 6;
    const int lo   = lane & 15;
    const int hi   = lane >> 4;

    f32x4 acc[4][8];
#pragma unroll
    for (int mi = 0; mi < 4; ++mi)
#pragma unroll
        for (int ni = 0; ni < 8; ++ni) acc[mi][ni] = (f32x4){0.f, 0.f, 0.f, 0.f};

    const float* xslab = x + (size_t)b_ * 512 * 4096 + (size_t)(wh * 32 + rb * 2) * 64;
    const int tq = tid & 31;      // token-quad
    const int cs = tid >> 5;      // channel slab of 4
    const float* xpbase = xslab + (size_t)(cs * 4) * 4096 + tq * 4;

    f32x4 bregs[4];

#define K1_ISSUE_A(KT, BUF)                                                        \
    {                                                                              \
        const char* src_ = (const char*)wt + (size_t)(KT) * 16384;                 \
        char* dst_ = smem + (BUF) * 16384;                                         \
        _Pragma("unroll")                                                          \
        for (int r_ = 0; r_ < 4; ++r_) {                                           \
            int idx_ = (r_ * 256 + tid) * 16;                                      \
            gload_lds16(src_ + idx_, dst_ + idx_);                                 \
        }                                                                          \
    }
#define K1_LOAD_B(KT)                                                              \
    {                                                                              \
        const float* xp_ = xpbase + (size_t)(KT) * 32 * 4096;                      \
        _Pragma("unroll")                                                          \
        for (int c_ = 0; c_ < 4; ++c_) bregs[c_] = *(const f32x4*)(xp_ + (size_t)c_ * 4096); \
    }
#define K1_WRITE_B(BUF)                                                            \
    {                                                                              \
        char* lb_ = smem + 32768 + (BUF) * 10240;                                  \
        _Pragma("unroll")                                                          \
        for (int e_ = 0; e_ < 4; ++e_) {                                           \
            ushort4v u_ = {f2bf(bregs[0][e_]), f2bf(bregs[1][e_]),                 \
                           f2bf(bregs[2][e_]), f2bf(bregs[3][e_])};                \
            *(ushort4v*)(lb_ + (tq * 4 + e_) * 80 + cs * 8) = u_;                  \
        }                                                                          \
    }

    K1_ISSUE_A(0, 0);
    K1_LOAD_B(0);
    K1_WRITE_B(0);
    K1_LOAD_B(1);
    LGKM0();
    __builtin_amdgcn_s_barrier();

    for (int kt = 0; kt < 16; ++kt) {
        const int b = kt & 1;
        {
            const int ktn = (kt + 1 < 16) ? kt + 1 : 15;
            K1_ISSUE_A(ktn, b ^ 1);
        }
        short8 af[4], bfr[8];
#pragma unroll
        for (int mi = 0; mi < 4; ++mi) {
            int base = (hi * 256 + wv * 64 + mi * 16 + lo) * 16;
            af[mi] = *(const short8*)(smem + b * 16384 + (base ^ ((hi & 3) << 4)));
        }
#pragma unroll
        for (int ni = 0; ni < 8; ++ni)
            bfr[ni] = *(const short8*)(smem + 32768 + b * 10240 + (ni * 16 + lo) * 80 + hi * 16);
        __builtin_amdgcn_s_setprio(1);
#pragma unroll
        for (int mi = 0; mi < 4; ++mi)
#pragma unroll
            for (int ni = 0; ni < 8; ++ni)
                acc[mi][ni] = __builtin_amdgcn_mfma_f32_16x16x32_bf16(af[mi], bfr[ni], acc[mi][ni], 0, 0, 0);
        __builtin_amdgcn_s_setprio(0);
        K1_WRITE_B(b ^ 1);
        __builtin_amdgcn_sched_barrier(0);
        {
            const int ktn2 = (kt + 2 < 16) ? kt + 2 : 15;
            K1_LOAD_B(ktn2);
        }
        VMCNT(4);
        LGKM0();
        __builtin_amdgcn_s_barrier();
    }
    VMCNT(0);

    float part[8];
#pragma unroll
    for (int ni = 0; ni < 8; ++ni) {
        float s = 0.f;
#pragma unroll
        for (int mi = 0; mi < 4; ++mi)
#pragma unroll
            for (int r = 0; r < 4; ++r) s += acc[mi][ni][r] * acc[mi][ni][r];
        s += __shfl_xor(s, 16);
        s += __shfl_xor(s, 32);
        part[ni] = s;
    }
    if (hi == 0) {
#pragma unroll
        for (int ni = 0; ni < 8; ++ni)
            *(float*)(smem + 53248 + (wv * 128 + ni * 16 + lo) * 4) = part[ni];
    }
    __syncthreads();

    float inv[8];
#pragma unroll
    for (int ni = 0; ni < 8; ++ni) {
        const int tl = ni * 16 + lo;
        float s = *(const float*)(smem + 53248 + (0 * 128 + tl) * 4)
                + *(const float*)(smem + 53248 + (1 * 128 + tl) * 4)
                + *(const float*)(smem + 53248 + (2 * 128 + tl) * 4)
                + *(const float*)(smem + 53248 + (3 * 128 + tl) * 4);
        inv[ni] = 1.f / (sqrtf(s) + 1e-6f);
    }

    // stage normalized fp8 into sQ: row f (256B), byte c ^ ((f&3)<<4)
#pragma unroll
    for (int ni = 0; ni < 8; ++ni) {
        const int f    = ni * 16 + lo;
        const int swzf = (f & 3) << 4;
#pragma unroll
        for (int mi = 0; mi < 4; ++mi) {
            const int c = wv * 64 + mi * 16 + hi * 4;
            unsigned int u = pk_fp8x4(acc[mi][ni][0] * inv[ni], acc[mi][ni][1] * inv[ni],
                                      acc[mi][ni][2] * inv[ni], acc[mi][ni][3] * inv[ni]);
            *(unsigned int*)(smem + f * 256 + (c ^ swzf)) = u;
        }
    }
    __syncthreads();

#pragma unroll
    for (int it = 0; it < 8; ++it) {
        const int unit = it * 256 + tid;
        const int f    = unit >> 4;
        const int c16  = (unit & 15) * 16;
        f32x4 d = *(const f32x4*)(smem + f * 256 + (c16 ^ ((f & 3) << 4)));
        const int ww  = (f >> 5) & 1;
        const int rho = f >> 6;
        const int rq  = rb * 64 + rho * 32 + (f & 31);
        char* qw = (char*)qn + (size_t)(winbase + ww) * (1024 * 256);
        *(f32x4*)(qw + (size_t)rq * 256 + (c16 ^ ((rq & 3) << 4))) = d;
    }
}

// ---------------- K2: fp8 S^T + PV with counted-prefetch dbuf pipeline ----------------
// grid: 512 = 128 windows * 4 query-blocks (256 q); bid&127 = window (XCD swizzle).
// Per chunk: DMA(chk+1) issued at top; V(chk+2) reg-prefetched; VMCNT(1) (leaves V-load
// in flight); ONE barrier/chunk. LDS: lK dbuf 32KB + lP 36KB + lV dbuf 4.5KB = 72.5KB.
__global__ __launch_bounds__(256, 2) void k2_attn(const unsigned char* __restrict__ qn,
                                                  const float* __restrict__ v,
                                                  float* __restrict__ out) {
    const int g   = blockIdx.x;
    const int win = g & 127;
    const int qb  = g >> 7;
    const int b_  = win >> 2;
    const int h0  = ((win >> 1) & 1) << 5;
    const int w0  = (win & 1) << 5;

    __shared__ __align__(16) char lK[2][64 * 256];          // fp8 key image, 2x16 KB
    __shared__ __align__(16) unsigned short lP[256][72];    // P bf16 [q][key], 36 KB
    __shared__ __align__(16) unsigned short lV[2][16][72];  // V^T dbuf, row15 = ones

    const int tid  = threadIdx.x;
    const int lane = tid & 63;
    const int wv   = tid >> 6;
    const int lo   = lane & 15;
    const int hi   = lane >> 4;

    const unsigned char* qwin = qn + (size_t)win * (1024 * 256);
    const int qw0 = qb * 256 + wv * 64;

    long qa8[4][8];
#pragma unroll
    for (int mi = 0; mi < 4; ++mi) {
        const int rq = qw0 + mi * 16 + lo;
        const size_t swz = (size_t)((rq & 3) << 4);
#pragma unroll
        for (int kc = 0; kc < 8; ++kc)
            qa8[mi][kc] = *(const long*)(qwin + (((size_t)rq * 256 + kc * 32 + hi * 8) ^ swz));
    }

    f32x4 accout[4];
#pragma unroll
    for (int t = 0; t < 4; ++t) accout[t] = (f32x4){0.f, 0.f, 0.f, 0.f};

    const float* vbase = v + (size_t)b_ * 15 * 4096 + (size_t)h0 * 64 + w0;
    const int chn = tid & 15;
    const int kp  = tid >> 4;
    const float* vch = vbase + (size_t)(chn < 15 ? chn : 14) * 4096;  // clamped, uniform issue
    char* lPb = (char*)&lP[0][0];

#define K2_VADDR(CHK) (vch + ((((CHK) * 64 + kp * 4) >> 5) * 64 + (((CHK) * 64 + kp * 4) & 31)))
#define K2_WRITE_V(BUF, D)                                                         \
    {                                                                              \
        uint32x2 u_;                                                               \
        if (chn < 15) { u_[0] = pack2((D)[0], (D)[1]); u_[1] = pack2((D)[2], (D)[3]); } \
        else          { u_[0] = 0x3F803F80u;           u_[1] = 0x3F803F80u; }      \
        *(uint32x2*)((char*)lV[BUF] + chn * 144 + kp * 8) = u_;                    \
    }
#define K2_ISSUE_K(CHK, BUF)                                                       \
    {                                                                              \
        const char* src_ = (const char*)qwin + (size_t)(CHK) * 16384;              \
        char* dst_ = (char*)lK[BUF];                                               \
        _Pragma("unroll")                                                          \
        for (int r_ = 0; r_ < 4; ++r_) {                                           \
            int idx_ = (r_ * 256 + tid) * 16;                                      \
            gload_lds16(src_ + idx_, dst_ + idx_);                                 \
        }                                                                          \
    }

    f32x4 vpre;
    // ---- prologue: chunk 0 staged; V(1) in flight ----
    {
        f32x4 d0 = *(const f32x4*)K2_VADDR(0);
        K2_WRITE_V(0, d0);                 // consumes d0 (auto-wait; nothing else in flight)
    }
    K2_ISSUE_K(0, 0);                      // 4 DMA
    vpre = *(const f32x4*)K2_VADDR(1);     // 1 load
    VMCNT(1);                              // DMA(0) done; vpre may pend
    LGKM0();
    __builtin_amdgcn_s_barrier();

    for (int chk = 0; chk < 16; ++chk) {
        const int b = chk & 1;
        // 1. DMA next chunk into lK[b^1] (its readers finished before the barrier)
        {
            const int cn = (chk + 1 < 16) ? chk + 1 : 15;
            K2_ISSUE_K(cn, b ^ 1);
        }
        // 2. write lV[b^1] <- vpre (auto-wait = vmcnt(4): DMA stays in flight)
        K2_WRITE_V(b ^ 1, vpre);
        // 3. pin order, then issue V(chk+2)
        __builtin_amdgcn_sched_barrier(0);
        {
            const int cv = (chk + 2 < 16) ? chk + 2 : 15;
            vpre = *(const f32x4*)K2_VADDR(cv);
        }
        __builtin_amdgcn_sched_barrier(0);

        // 4. compute S^T + PV on lK[b], lV[b]
        const char* lKb = (const char*)lK[b];
#pragma unroll
        for (int ni = 0; ni < 4; ++ni) {
            f32x4 st[4];
#pragma unroll
            for (int mi = 0; mi < 4; ++mi) st[mi] = (f32x4){0.f, 0.f, 0.f, 0.f};
            __builtin_amdgcn_s_setprio(1);
#pragma unroll
            for (int kc = 0; kc < 8; ++kc) {
                const int row = ni * 16 + lo;
                const int off = ((row * 256) + kc * 32 + hi * 8) ^ ((row & 3) << 4);
                long kb = *(const long*)(lKb + off);
#pragma unroll
                for (int mi = 0; mi < 4; ++mi)
                    st[mi] = __builtin_amdgcn_mfma_f32_16x16x32_fp8_fp8(kb, qa8[mi][kc], st[mi], 0, 0, 0);
            }
            __builtin_amdgcn_s_setprio(0);
#pragma unroll
            for (int mi = 0; mi < 4; ++mi) {
                uint32x2 u;
                u[0] = pack2(fmaxf(st[mi][0], 0.f), fmaxf(st[mi][1], 0.f));
                u[1] = pack2(fmaxf(st[mi][2], 0.f), fmaxf(st[mi][3], 0.f));
                *(uint32x2*)(lPb + (wv * 64 + mi * 16 + lo) * 144 + ni * 32 + hi * 8) = u;
            }
        }
        __builtin_amdgcn_s_setprio(1);
#pragma unroll
        for (int t = 0; t < 4; ++t) {
#pragma unroll
            for (int ks = 0; ks < 2; ++ks) {
                short8 pa  = *(const short8*)(lPb + (wv * 64 + t * 16 + lo) * 144 + ks * 64 + hi * 16);
                short8 vbf = *(const short8*)((const char*)lV[b] + lo * 144 + ks * 64 + hi * 16);
                accout[t] = __builtin_amdgcn_mfma_f32_16x16x32_bf16(pa, vbf, accout[t], 0, 0, 0);
            }
        }
        __builtin_amdgcn_s_setprio(0);

        // 5. wait: 4 DMA done (vpre may pend); publish lV/lP writes; release buffers
        VMCNT(1);
        LGKM0();
        __builtin_amdgcn_s_barrier();
    }
    VMCNT(0);   // drain tail prefetches

    // epilogue: divide by rowsum (ch 15) and store
#pragma unroll
    for (int t = 0; t < 4; ++t) {
#pragma unroll
        for (int r = 0; r < 4; ++r) {
            float rs = __shfl(accout[t][r], (lane & 48) | 15);
            if (lo < 15) {
                int q = qw0 + t * 16 + hi * 4 + r;
                out[(size_t)(b_ * 15 + lo) * 4096 + (size_t)(h0 + (q >> 5)) * 64 + (w0 + (q & 31))] =
                    accout[t][r] / (rs + 1e-6f);
            }
        }
    }
}

extern "C" void kernel_launch(void* const* d_in, const int* in_sizes, int n_in,
                              void* d_out, int out_size, void* d_ws, size_t ws_size,
                              hipStream_t stream) {
    const float* x = (const float*)d_in[0];
    const float* v = (const float*)d_in[1];
    const float* w = (const float*)d_in[2];
    float* out = (float*)d_out;

    unsigned char*  qn = (unsigned char*)d_ws;                           // 32 MiB fp8 (swizzled)
    unsigned short* wt = (unsigned short*)((char*)d_ws + (size_t)32 * 1024 * 1024);  // 256 KiB tiled W

    k0_wt<<<64, 256, 0, stream>>>(w, wt);
    k1_qgemm<<<1024, 256, 0, stream>>>(x, wt, qn);
    k2_attn<<<512, 256, 0, stream>>>(qn, v, out);
}

// Round 16
// 118.268 us; speedup vs baseline: 1.0659x; 1.0659x over previous
//
#include <hip/hip_runtime.h>
#include <hip/hip_bf16.h>

typedef __attribute__((ext_vector_type(8))) short short8;       // 8 x bf16 (4 VGPR)
typedef __attribute__((ext_vector_type(4))) float f32x4;        // MFMA acc / float4
typedef __attribute__((ext_vector_type(2))) float f32x2;
typedef __attribute__((ext_vector_type(4))) unsigned short ushort4v;
typedef __attribute__((ext_vector_type(2))) unsigned int uint32x2;
typedef __attribute__((ext_vector_type(4))) int int4v;
typedef __attribute__((ext_vector_type(8))) int int8v;

__device__ __forceinline__ unsigned short f2bf(float f) {
    __hip_bfloat16 h = __float2bfloat16(f);
    return __builtin_bit_cast(unsigned short, h);
}
__device__ __forceinline__ unsigned int pack2(float a, float b) {
    return (unsigned int)f2bf(a) | ((unsigned int)f2bf(b) << 16);
}
__device__ __forceinline__ unsigned int pk_fp8x4(float a0, float a1, float a2, float a3) {
    int v = 0;
    v = __builtin_amdgcn_cvt_pk_fp8_f32(a0, a1, v, false);   // bytes 0,1
    v = __builtin_amdgcn_cvt_pk_fp8_f32(a2, a3, v, true);    // bytes 2,3
    return (unsigned int)v;
}
__device__ __forceinline__ void gload_lds16(const void* g, void* l) {
    __builtin_amdgcn_global_load_lds((const __attribute__((address_space(1))) unsigned int*)g,
                                     (__attribute__((address_space(3))) unsigned int*)l, 16, 0, 0);
}

#define VMCNT(N) asm volatile("s_waitcnt vmcnt(" #N ")" ::: "memory")
#define LGKM0()  asm volatile("s_waitcnt lgkmcnt(0)" ::: "memory")

// ---------------- K0: W fp32 [256][512] -> wt bf16 tiled+bank-swizzled (R14 verbatim) ----
__global__ __launch_bounds__(256) void k0_wt(const float* __restrict__ w,
                                             unsigned short* __restrict__ wt) {
    int T = blockIdx.x * 256 + threadIdx.x;     // 0..16383 slots
    int c = T & 255, u = T >> 8;
    const float* s = w + c * 512 + u * 8;
    f32x4 a = *(const f32x4*)s;
    f32x4 b = *(const f32x4*)(s + 4);
    short8 o;
    o[0] = (short)f2bf(a[0]); o[1] = (short)f2bf(a[1]);
    o[2] = (short)f2bf(a[2]); o[3] = (short)f2bf(a[3]);
    o[4] = (short)f2bf(b[0]); o[5] = (short)f2bf(b[1]);
    o[6] = (short)f2bf(b[2]); o[7] = (short)f2bf(b[3]);
    size_t off = (size_t)(((u * 256 + c) * 16) ^ ((u & 3) << 4));
    *(short8*)((char*)wt + off) = o;
}

// ---------------- K1: Q-GEMM + normalize (R14 verbatim) ----------------
__global__ __launch_bounds__(256, 2) void k1_qgemm(const float* __restrict__ x,
                                                   const unsigned short* __restrict__ wt,
                                                   unsigned char* __restrict__ qn) {
    const int blk = blockIdx.x;
    const int b_  = blk >> 5;
    const int wh  = (blk >> 4) & 1;
    const int rb  = blk & 15;
    const int winbase = b_ * 4 + wh * 2;

    __shared__ __align__(16) char smem[65536];

    const int tid  = threadIdx.x;
    const int lane = tid & 63;
    const int wv   = tid >> 6;
    const int lo   = lane & 15;
    const int hi   = lane >> 4;

    f32x4 acc[4][8];
#pragma unroll
    for (int mi = 0; mi < 4; ++mi)
#pragma unroll
        for (int ni = 0; ni < 8; ++ni) acc[mi][ni] = (f32x4){0.f, 0.f, 0.f, 0.f};

    const float* xslab = x + (size_t)b_ * 512 * 4096 + (size_t)(wh * 32 + rb * 2) * 64;
    const int tq = tid & 31;      // token-quad
    const int cs = tid >> 5;      // channel slab of 4
    const float* xpbase = xslab + (size_t)(cs * 4) * 4096 + tq * 4;

    f32x4 bregs[4];

#define K1_ISSUE_A(KT, BUF)                                                        \
    {                                                                              \
        const char* src_ = (const char*)wt + (size_t)(KT) * 16384;                 \
        char* dst_ = smem + (BUF) * 16384;                                         \
        _Pragma("unroll")                                                          \
        for (int r_ = 0; r_ < 4; ++r_) {                                           \
            int idx_ = (r_ * 256 + tid) * 16;                                      \
            gload_lds16(src_ + idx_, dst_ + idx_);                                 \
        }                                                                          \
    }
#define K1_LOAD_B(KT)                                                              \
    {                                                                              \
        const float* xp_ = xpbase + (size_t)(KT) * 32 * 4096;                      \
        _Pragma("unroll")                                                          \
        for (int c_ = 0; c_ < 4; ++c_) bregs[c_] = *(const f32x4*)(xp_ + (size_t)c_ * 4096); \
    }
#define K1_WRITE_B(BUF)                                                            \
    {                                                                              \
        char* lb_ = smem + 32768 + (BUF) * 10240;                                  \
        _Pragma("unroll")                                                          \
        for (int e_ = 0; e_ < 4; ++e_) {                                           \
            ushort4v u_ = {f2bf(bregs[0][e_]), f2bf(bregs[1][e_]),                 \
                           f2bf(bregs[2][e_]), f2bf(bregs[3][e_])};                \
            *(ushort4v*)(lb_ + (tq * 4 + e_) * 80 + cs * 8) = u_;                  \
        }                                                                          \
    }

    K1_ISSUE_A(0, 0);
    K1_LOAD_B(0);
    K1_WRITE_B(0);
    K1_LOAD_B(1);
    LGKM0();
    __builtin_amdgcn_s_barrier();

    for (int kt = 0; kt < 16; ++kt) {
        const int b = kt & 1;
        {
            const int ktn = (kt + 1 < 16) ? kt + 1 : 15;
            K1_ISSUE_A(ktn, b ^ 1);
        }
        short8 af[4], bfr[8];
#pragma unroll
        for (int mi = 0; mi < 4; ++mi) {
            int base = (hi * 256 + wv * 64 + mi * 16 + lo) * 16;
            af[mi] = *(const short8*)(smem + b * 16384 + (base ^ ((hi & 3) << 4)));
        }
#pragma unroll
        for (int ni = 0; ni < 8; ++ni)
            bfr[ni] = *(const short8*)(smem + 32768 + b * 10240 + (ni * 16 + lo) * 80 + hi * 16);
        __builtin_amdgcn_s_setprio(1);
#pragma unroll
        for (int mi = 0; mi < 4; ++mi)
#pragma unroll
            for (int ni = 0; ni < 8; ++ni)
                acc[mi][ni] = __builtin_amdgcn_mfma_f32_16x16x32_bf16(af[mi], bfr[ni], acc[mi][ni], 0, 0, 0);
        __builtin_amdgcn_s_setprio(0);
        K1_WRITE_B(b ^ 1);
        __builtin_amdgcn_sched_barrier(0);
        {
            const int ktn2 = (kt + 2 < 16) ? kt + 2 : 15;
            K1_LOAD_B(ktn2);
        }
        VMCNT(4);
        LGKM0();
        __builtin_amdgcn_s_barrier();
    }
    VMCNT(0);

    float part[8];
#pragma unroll
    for (int ni = 0; ni < 8; ++ni) {
        float s = 0.f;
#pragma unroll
        for (int mi = 0; mi < 4; ++mi)
#pragma unroll
            for (int r = 0; r < 4; ++r) s += acc[mi][ni][r] * acc[mi][ni][r];
        s += __shfl_xor(s, 16);
        s += __shfl_xor(s, 32);
        part[ni] = s;
    }
    if (hi == 0) {
#pragma unroll
        for (int ni = 0; ni < 8; ++ni)
            *(float*)(smem + 53248 + (wv * 128 + ni * 16 + lo) * 4) = part[ni];
    }
    __syncthreads();

    float inv[8];
#pragma unroll
    for (int ni = 0; ni < 8; ++ni) {
        const int tl = ni * 16 + lo;
        float s = *(const float*)(smem + 53248 + (0 * 128 + tl) * 4)
                + *(const float*)(smem + 53248 + (1 * 128 + tl) * 4)
                + *(const float*)(smem + 53248 + (2 * 128 + tl) * 4)
                + *(const float*)(smem + 53248 + (3 * 128 + tl) * 4);
        inv[ni] = 1.f / (sqrtf(s) + 1e-6f);
    }

    // stage normalized fp8 into sQ: row f (256B), byte c ^ ((f&3)<<4)
#pragma unroll
    for (int ni = 0; ni < 8; ++ni) {
        const int f    = ni * 16 + lo;
        const int swzf = (f & 3) << 4;
#pragma unroll
        for (int mi = 0; mi < 4; ++mi) {
            const int c = wv * 64 + mi * 16 + hi * 4;
            unsigned int u = pk_fp8x4(acc[mi][ni][0] * inv[ni], acc[mi][ni][1] * inv[ni],
                                      acc[mi][ni][2] * inv[ni], acc[mi][ni][3] * inv[ni]);
            *(unsigned int*)(smem + f * 256 + (c ^ swzf)) = u;
        }
    }
    __syncthreads();

#pragma unroll
    for (int it = 0; it < 8; ++it) {
        const int unit = it * 256 + tid;
        const int f    = unit >> 4;
        const int c16  = (unit & 15) * 16;
        f32x4 d = *(const f32x4*)(smem + f * 256 + (c16 ^ ((f & 3) << 4)));
        const int ww  = (f >> 5) & 1;
        const int rho = f >> 6;
        const int rq  = rb * 64 + rho * 32 + (f & 31);
        char* qw = (char*)qn + (size_t)(winbase + ww) * (1024 * 256);
        *(f32x4*)(qw + (size_t)rq * 256 + (c16 ^ ((rq & 3) << 4))) = d;
    }
}

// ---------------- K2: S^T via MX-scaled fp8 K=128 MFMA + PV (pipeline = R15) ----------------
// grid: 512 = 128 windows * 4 query-blocks (256 q); bid&127 = window (XCD swizzle).
// S-MFMA: mfma_scale_f32_16x16x128_f8f6f4, fmt=fp8(e4m3), scales=1.0 (0x7F E8M0).
// A/B fragment: lane(lo,hi): row=lo(+tile), k = hi*32 + e  (32 fp8 = 2x16B chunks, XOR-swizzled).
// C/D layout identical to 16x16x32 (shape-determined) -> P-write/PV/epilogue unchanged.
__global__ __launch_bounds__(256, 2) void k2_attn(const unsigned char* __restrict__ qn,
                                                  const float* __restrict__ v,
                                                  float* __restrict__ out) {
    const int g   = blockIdx.x;
    const int win = g & 127;
    const int qb  = g >> 7;
    const int b_  = win >> 2;
    const int h0  = ((win >> 1) & 1) << 5;
    const int w0  = (win & 1) << 5;

    __shared__ __align__(16) char lK[2][64 * 256];          // fp8 key image, 2x16 KB
    __shared__ __align__(16) unsigned short lP[256][72];    // P bf16 [q][key], 36 KB
    __shared__ __align__(16) unsigned short lV[2][16][72];  // V^T dbuf, row15 = ones

    const int tid  = threadIdx.x;
    const int lane = tid & 63;
    const int wv   = tid >> 6;
    const int lo   = lane & 15;
    const int hi   = lane >> 4;

    const unsigned char* qwin = qn + (size_t)win * (1024 * 256);
    const int qw0 = qb * 256 + wv * 64;

    // hoisted Q fragments: per mi, kc(2): 32 fp8 (k = kc*128 + hi*32 + [0..31])
    int8v qa[4][2];
#pragma unroll
    for (int mi = 0; mi < 4; ++mi) {
        const int rq = qw0 + mi * 16 + lo;
        const size_t swz = (size_t)((rq & 3) << 4);
#pragma unroll
        for (int kc = 0; kc < 2; ++kc) {
            const size_t base = (size_t)rq * 256 + kc * 128 + hi * 32;
            int4v c0 = *(const int4v*)(qwin + (base ^ swz));
            int4v c1 = *(const int4v*)(qwin + ((base + 16) ^ swz));
            int8v q8;
            q8[0] = c0[0]; q8[1] = c0[1]; q8[2] = c0[2]; q8[3] = c0[3];
            q8[4] = c1[0]; q8[5] = c1[1]; q8[6] = c1[2]; q8[7] = c1[3];
            qa[mi][kc] = q8;
        }
    }

    f32x4 accout[4];
#pragma unroll
    for (int t = 0; t < 4; ++t) accout[t] = (f32x4){0.f, 0.f, 0.f, 0.f};

    const float* vbase = v + (size_t)b_ * 15 * 4096 + (size_t)h0 * 64 + w0;
    const int chn = tid & 15;
    const int kp  = tid >> 4;
    const float* vch = vbase + (size_t)(chn < 15 ? chn : 14) * 4096;  // clamped, uniform issue
    char* lPb = (char*)&lP[0][0];

#define K2_VADDR(CHK) (vch + ((((CHK) * 64 + kp * 4) >> 5) * 64 + (((CHK) * 64 + kp * 4) & 31)))
#define K2_WRITE_V(BUF, D)                                                         \
    {                                                                              \
        uint32x2 u_;                                                               \
        if (chn < 15) { u_[0] = pack2((D)[0], (D)[1]); u_[1] = pack2((D)[2], (D)[3]); } \
        else          { u_[0] = 0x3F803F80u;           u_[1] = 0x3F803F80u; }      \
        *(uint32x2*)((char*)lV[BUF] + chn * 144 + kp * 8) = u_;                    \
    }
#define K2_ISSUE_K(CHK, BUF)                                                       \
    {                                                                              \
        const char* src_ = (const char*)qwin + (size_t)(CHK) * 16384;              \
        char* dst_ = (char*)lK[BUF];                                               \
        _Pragma("unroll")                                                          \
        for (int r_ = 0; r_ < 4; ++r_) {                                           \
            int idx_ = (r_ * 256 + tid) * 16;                                      \
            gload_lds16(src_ + idx_, dst_ + idx_);                                 \
        }                                                                          \
    }

    f32x4 vpre;
    // ---- prologue: chunk 0 staged; V(1) in flight ----
    {
        f32x4 d0 = *(const f32x4*)K2_VADDR(0);
        K2_WRITE_V(0, d0);
    }
    K2_ISSUE_K(0, 0);
    vpre = *(const f32x4*)K2_VADDR(1);
    VMCNT(1);
    LGKM0();
    __builtin_amdgcn_s_barrier();

    for (int chk = 0; chk < 16; ++chk) {
        const int b = chk & 1;
        // 1. DMA next chunk into lK[b^1]
        {
            const int cn = (chk + 1 < 16) ? chk + 1 : 15;
            K2_ISSUE_K(cn, b ^ 1);
        }
        // 2. write lV[b^1] <- vpre
        K2_WRITE_V(b ^ 1, vpre);
        // 3. pin order, then issue V(chk+2)
        __builtin_amdgcn_sched_barrier(0);
        {
            const int cv = (chk + 2 < 16) ? chk + 2 : 15;
            vpre = *(const f32x4*)K2_VADDR(cv);
        }
        __builtin_amdgcn_sched_barrier(0);

        // 4. S^T via MX-fp8 K=128 + PV on lK[b], lV[b]
        const char* lKb = (const char*)lK[b];
#pragma unroll
        for (int ni = 0; ni < 4; ++ni) {
            f32x4 st[4];
#pragma unroll
            for (int mi = 0; mi < 4; ++mi) st[mi] = (f32x4){0.f, 0.f, 0.f, 0.f};
            __builtin_amdgcn_s_setprio(1);
#pragma unroll
            for (int kc = 0; kc < 2; ++kc) {
                const int row  = ni * 16 + lo;
                const int swz  = (row & 3) << 4;
                const int base = row * 256 + kc * 128 + hi * 32;
                int4v c0 = *(const int4v*)(lKb + (base ^ swz));
                int4v c1 = *(const int4v*)(lKb + ((base + 16) ^ swz));
                int8v kb;
                kb[0] = c0[0]; kb[1] = c0[1]; kb[2] = c0[2]; kb[3] = c0[3];
                kb[4] = c1[0]; kb[5] = c1[1]; kb[6] = c1[2]; kb[7] = c1[3];
#pragma unroll
                for (int mi = 0; mi < 4; ++mi)
                    st[mi] = __builtin_amdgcn_mfma_scale_f32_16x16x128_f8f6f4(
                                 kb, qa[mi][kc], st[mi],
                                 0 /*cbsz: fp8*/, 0 /*blgp: fp8*/,
                                 0, 0x7F7F7F7F /*scaleA = 1.0*/,
                                 0, 0x7F7F7F7F /*scaleB = 1.0*/);
            }
            __builtin_amdgcn_s_setprio(0);
#pragma unroll
            for (int mi = 0; mi < 4; ++mi) {
                uint32x2 u;
                u[0] = pack2(fmaxf(st[mi][0], 0.f), fmaxf(st[mi][1], 0.f));
                u[1] = pack2(fmaxf(st[mi][2], 0.f), fmaxf(st[mi][3], 0.f));
                *(uint32x2*)(lPb + (wv * 64 + mi * 16 + lo) * 144 + ni * 32 + hi * 8) = u;
            }
        }
        __builtin_amdgcn_s_setprio(1);
#pragma unroll
        for (int t = 0; t < 4; ++t) {
#pragma unroll
            for (int ks = 0; ks < 2; ++ks) {
                short8 pa  = *(const short8*)(lPb + (wv * 64 + t * 16 + lo) * 144 + ks * 64 + hi * 16);
                short8 vbf = *(const short8*)((const char*)lV[b] + lo * 144 + ks * 64 + hi * 16);
                accout[t] = __builtin_amdgcn_mfma_f32_16x16x32_bf16(pa, vbf, accout[t], 0, 0, 0);
            }
        }
        __builtin_amdgcn_s_setprio(0);

        // 5. wait: 4 DMA done (vpre may pend); publish lV/lP writes; release buffers
        VMCNT(1);
        LGKM0();
        __builtin_amdgcn_s_barrier();
    }
    VMCNT(0);

    // epilogue: divide by rowsum (ch 15) and store
#pragma unroll
    for (int t = 0; t < 4; ++t) {
#pragma unroll
        for (int r = 0; r < 4; ++r) {
            float rs = __shfl(accout[t][r], (lane & 48) | 15);
            if (lo < 15) {
                int q = qw0 + t * 16 + hi * 4 + r;
                out[(size_t)(b_ * 15 + lo) * 4096 + (size_t)(h0 + (q >> 5)) * 64 + (w0 + (q & 31))] =
                    accout[t][r] / (rs + 1e-6f);
            }
        }
    }
}

extern "C" void kernel_launch(void* const* d_in, const int* in_sizes, int n_in,
                              void* d_out, int out_size, void* d_ws, size_t ws_size,
                              hipStream_t stream) {
    const float* x = (const float*)d_in[0];
    const float* v = (const float*)d_in[1];
    const float* w = (const float*)d_in[2];
    float* out = (float*)d_out;

    unsigned char*  qn = (unsigned char*)d_ws;                           // 32 MiB fp8 (swizzled)
    unsigned short* wt = (unsigned short*)((char*)d_ws + (size_t)32 * 1024 * 1024);  // 256 KiB tiled W

    k0_wt<<<64, 256, 0, stream>>>(w, wt);
    k1_qgemm<<<1024, 256, 0, stream>>>(x, wt, qn);
    k2_attn<<<512, 256, 0, stream>>>(qn, v, out);
}